// Round 10
// baseline (468.929 us; speedup 1.0000x reference)
//
#include <hip/hip_runtime.h>
#include <hip/hip_bf16.h>
#include <math.h>

// AFNO2D: rfft2(128x128, ortho) -> blockdiag complex MLP (8 x 96) -> softshrink -> irfft2 -> +bias
// B=4, H=W=128, C=768.  ALL transforms are MFMA GEMMs against baked bf16 matrices.
// Planes in ws (packed bf16 re|im per uint, [b][pos=h*65+kw][c]):
//   A = forward spectrum (written by k_fft_w, read-only afterwards)
//   Bp = post-MLP spectrum (written by k_mid)
// Bias via spectral identity: irfft_w(rfft_w(x)) = x, so k_ifft_w transforms (A + Bp) and
// never re-reads x (saves 402 MB HBM).
// k_mid v4: 2 WG/CU (76 KB LDS, VGPR<=64 via __launch_bounds__(1024,8)); MLP weight frags
// double-buffered 12 at a time (kk-pair {k,k+3} uses exactly stored-kk'=k via the Waug dedup).

#define HD   768
#define NBLK 8
#define HH   128
#define WW   128
#define WC   65
#define NPOS (HH * WC)

constexpr float SC    = 0.08838834764831845f;      // 1/sqrt(128)
constexpr float TWOPI = 6.28318530717958647692f;

// table layout (ushort offsets from wf base)
constexpr int TM_OFF     = 0;        // H-DFT: 96 frags = part(3:cos,sin,-sin) x kot(8) x kk(4)
constexpr int TW_OFF     = 49152;    // W-rfft: 40 frags = mt(10) x kk(4)
constexpr int TWI_OFF    = 69632;    // W-irfft: 40 frags = mt(8) x kk(5)
constexpr int WF_OFF     = 90112;    // MLP: 16 (layer,n) x 72 frags (k_mid uses kk' 0..2 = 36)
constexpr int WF_END_U16 = 679936;   // WF_OFF + 16*72*512
constexpr size_t A_UINTS = (size_t)4 * NPOS * HD;  // 102.2 MB per plane

typedef __attribute__((ext_vector_type(8))) short short8;
typedef __attribute__((ext_vector_type(4))) float f32x4;

#define MFMA __builtin_amdgcn_mfma_f32_16x16x32_bf16

static __device__ inline unsigned short f2bf(float f) {
  __hip_bfloat16 h = __float2bfloat16(f);
  return __builtin_bit_cast(unsigned short, h);
}
static __device__ inline unsigned int pack2(float re, float im) {
  return (unsigned int)f2bf(re) | ((unsigned int)f2bf(im) << 16);
}
static __device__ inline float lo2f(unsigned int u) {
  return __builtin_bit_cast(float, u << 16);
}
static __device__ inline float hi2f(unsigned int u) {
  return __builtin_bit_cast(float, u & 0xffff0000u);
}

// ================= k_prep: bake all MFMA fragment images (unchanged from r9) ==========
__global__ __launch_bounds__(256) void k_prep(const float* __restrict__ w1,
                                              const float* __restrict__ b1,
                                              const float* __restrict__ w2,
                                              const float* __restrict__ b2,
                                              unsigned short* __restrict__ wf,
                                              float* __restrict__ bpk) {
  const int blk = blockIdx.x, t = threadIdx.x;
  if (blk < 16) {                      // MLP Waug B-frags (full 72) + biases
    const int layer = blk >> 3, n = blk & 7;
    const float* w  = layer ? w2 : w1;
    const float* bs = layer ? b2 : b1;
    unsigned short* dst = wf + WF_OFF + (size_t)blk * (72 * 512);
    for (int e = t; e < 72 * 512; e += 256) {
      int f = e >> 9, idx = e & 511;
      int kk = f / 12, nt = f - kk * 12;
      int lane = idx >> 3, j = idx & 7;
      int k  = kk * 32 + (lane >> 4) * 8 + j;     // 0..191
      int cc = nt * 16 + (lane & 15);             // 0..191
      float v;
      if (k < 96) v = (cc < 96) ? w[(size_t)n * 9216 + k * 96 + cc]
                                : w[(size_t)(8 + n) * 9216 + k * 96 + (cc - 96)];
      else        v = (cc < 96) ? -w[(size_t)(8 + n) * 9216 + (k - 96) * 96 + cc]
                                :  w[(size_t)n * 9216 + (k - 96) * 96 + (cc - 96)];
      dst[e] = f2bf(v);
    }
    for (int c = t; c < 192; c += 256)
      bpk[blk * 192 + c] = (c < 96) ? bs[n * 96 + c] : bs[(8 + n) * 96 + (c - 96)];
  } else if (blk == 16) {              // H-DFT twiddles: 3 parts x 32 (kot*4+kk)
    for (int e = t; e < 96 * 512; e += 256) {
      int f = e >> 9, idx = e & 511;
      int part = f >> 5, rem = f & 31, kot = rem >> 2, kk = rem & 3;
      int lane = idx >> 3, j = idx & 7;
      int ko = kot * 16 + (lane & 15);
      int r  = kk * 32 + (lane >> 4) * 8 + j;     // 0..127
      float sn, cs; sincosf((TWOPI / 128.f) * (float)((ko * r) & 127), &sn, &cs);
      float v = (part == 0) ? cs : (part == 1) ? sn : -sn;
      wf[TM_OFF + (size_t)f * 512 + idx] = f2bf(v * SC);
    }
  } else if (blk == 17) {              // W-rfft matrix: rows 0..79 = re, 80..159 = im
    for (int e = t; e < 40 * 512; e += 256) {
      int f = e >> 9, idx = e & 511;
      int mt = f >> 2, kk = f & 3;
      int lane = idx >> 3, j = idx & 7;
      int row = mt * 16 + (lane & 15);
      int r   = kk * 32 + (lane >> 4) * 8 + j;    // 0..127
      int kor = (row < 80) ? row : row - 80;
      float sn, cs; sincosf((TWOPI / 128.f) * (float)((kor * r) & 127), &sn, &cs);
      wf[TW_OFF + (size_t)f * 512 + idx] = f2bf((row < 80 ? cs : -sn) * SC);
    }
  } else {                             // W-irfft matrix: K = [re 0..79 | im 0..79]
    for (int e = t; e < 40 * 512; e += 256) {
      int f = e >> 9, idx = e & 511;
      int mt = f / 5, kk = f - mt * 5;
      int lane = idx >> 3, j = idx & 7;
      int wr = mt * 16 + (lane & 15);
      int k  = kk * 32 + (lane >> 4) * 8 + j;     // 0..159
      float v = 0.f;
      if (k < 80) {
        int kb = k;
        if (kb <= 64) {
          float sn, cs; sincosf((TWOPI / 128.f) * (float)((wr * kb) & 127), &sn, &cs);
          v = SC * ((kb == 0 || kb == 64) ? 1.f : 2.f) * cs;
        }
      } else {
        int kb = k - 80;                           // imag of bins 0,64 ignored (c2r)
        if (kb >= 1 && kb <= 63) {
          float sn, cs; sincosf((TWOPI / 128.f) * (float)((wr * kb) & 127), &sn, &cs);
          v = -2.f * SC * sn;
        }
      }
      wf[TWI_OFF + (size_t)f * 512 + idx] = f2bf(v);
    }
  }
}

// ================= k_fft_w: rfft along W via GEMM, x -> packed A =================
__global__ __launch_bounds__(256) void k_fft_w(const float* __restrict__ x,
                                               unsigned int* __restrict__ A,
                                               const unsigned short* __restrict__ wf) {
  __shared__ unsigned short Xt[64 * 136];          // [ch][r] bf16
  const int h = blockIdx.x, c0 = blockIdx.y * 64, b = blockIdx.z, t = threadIdx.x;
  const int wv = t >> 6, lane = t & 63, l15 = lane & 15, lg = lane >> 4;
  const float* xp = x + ((size_t)(b * HH + h)) * WW * HD + c0;
  for (int idx = t; idx < 128 * 64; idx += 256) {
    int r = idx >> 6, ch = idx & 63;
    Xt[ch * 136 + r] = f2bf(xp[(size_t)r * HD + ch]);
  }
  __syncthreads();
  const unsigned short* tw = wf + TW_OFF;
  f32x4 acc[10];
#pragma unroll
  for (int m = 0; m < 10; ++m) acc[m] = { 0.f, 0.f, 0.f, 0.f };
#pragma unroll
  for (int kk = 0; kk < 4; ++kk) {
    short8 bq = *(const short8*)&Xt[(wv * 16 + l15) * 136 + kk * 32 + lg * 8];
#pragma unroll
    for (int m = 0; m < 10; ++m) {
      short8 a = *(const short8*)&tw[(size_t)(m * 4 + kk) * 512 + lane * 8];
      acc[m] = MFMA(a, bq, acc[m], 0, 0, 0);
    }
  }
  unsigned int* Ao = A + ((size_t)b * NPOS + h * WC) * HD + c0 + wv * 16 + l15;
#pragma unroll
  for (int q = 0; q < 5; ++q)
#pragma unroll
    for (int r = 0; r < 4; ++r) {
      int ko = q * 16 + lg * 4 + r;
      if (ko <= 64) Ao[(size_t)ko * HD] = pack2(acc[q][r], acc[5 + q][r]);
    }
}

// ================= k_ifft_w: irfft along W of (A + Bp) via GEMM (spectral bias) ========
__global__ __launch_bounds__(256) void k_ifft_w(const unsigned int* __restrict__ A,
                                                const unsigned int* __restrict__ Bp,
                                                float* __restrict__ out,
                                                const unsigned short* __restrict__ wf) {
  __shared__ unsigned short Zt[64 * 168];          // [ch][k-stack 160]
  const int h = blockIdx.x, c0 = blockIdx.y * 64, b = blockIdx.z, t = threadIdx.x;
  const int wv = t >> 6, lane = t & 63, l15 = lane & 15, lg = lane >> 4;
  const size_t base = ((size_t)b * NPOS + h * WC) * HD + c0;
  for (int idx = t; idx < 65 * 64; idx += 256) {
    int kb = idx >> 6, ch = idx & 63;
    unsigned int uA = A[base + (size_t)kb * HD + ch];
    unsigned int uB = Bp[base + (size_t)kb * HD + ch];
    float re = lo2f(uA) + lo2f(uB);
    float im = hi2f(uA) + hi2f(uB);
    Zt[ch * 168 + kb]      = f2bf(re);
    Zt[ch * 168 + 80 + kb] = (kb == 0 || kb == 64) ? (unsigned short)0 : f2bf(im);
  }
  for (int idx = t; idx < 64 * 32; idx += 256) {   // zero-pad k 65..79 both halves
    int ch = idx >> 5, q = idx & 31;
    if (q < 30) {
      int kb = 65 + (q % 15), half = q / 15;
      Zt[ch * 168 + half * 80 + kb] = 0;
    }
  }
  __syncthreads();
  const unsigned short* twi = wf + TWI_OFF;
  f32x4 acc[8];
#pragma unroll
  for (int m = 0; m < 8; ++m) acc[m] = { 0.f, 0.f, 0.f, 0.f };
#pragma unroll
  for (int kk = 0; kk < 5; ++kk) {
    short8 bq = *(const short8*)&Zt[(wv * 16 + l15) * 168 + kk * 32 + lg * 8];
#pragma unroll
    for (int m = 0; m < 8; ++m) {
      short8 a = *(const short8*)&twi[(size_t)(m * 5 + kk) * 512 + lane * 8];
      acc[m] = MFMA(a, bq, acc[m], 0, 0, 0);
    }
  }
#pragma unroll
  for (int m = 0; m < 8; ++m)
#pragma unroll
    for (int r = 0; r < 4; ++r) {
      int wr = m * 16 + lg * 4 + r;
      size_t go = (((size_t)(b * HH + h)) * WW + wr) * HD + c0 + wv * 16 + l15;
      out[go] = acc[m][r];
    }
}

// ================= k_mid: H-DFT fwd + MLP + softshrink + H-DFT inv =====================
// 1024 threads, 76 KB LDS -> 2 WG/CU; VGPR pinned <=64 by __launch_bounds__(1024,8).
template <int FWD>
static __device__ inline void dft_gemm16(const unsigned short* Rb, const unsigned short* Ib,
                                         const unsigned short* tm, int rt, int cb, int lane,
                                         f32x4* aR, f32x4* aI) {
  const int l15 = lane & 15, lg = lane >> 4;
#pragma unroll
  for (int kkr = 0; kkr < 4; ++kkr) {
    const int r0 = kkr * 32 + lg * 8;
    short8 Ac = *(const short8*)&tm[(size_t)(0 * 32 + rt * 4 + kkr) * 512 + lane * 8];
    short8 As = *(const short8*)&tm[(size_t)(1 * 32 + rt * 4 + kkr) * 512 + lane * 8];
    short8 An = *(const short8*)&tm[(size_t)(2 * 32 + rt * 4 + kkr) * 512 + lane * 8];
#pragma unroll
    for (int c = 0; c < 3; ++c) {
      short8 zr = *(const short8*)&Rb[((cb + c) * 16 + l15) * 136 + r0];
      short8 zi = *(const short8*)&Ib[((cb + c) * 16 + l15) * 136 + r0];
      aR[c] = MFMA(Ac, zr, aR[c], 0, 0, 0);
      if constexpr (FWD) {
        aR[c] = MFMA(As, zi, aR[c], 0, 0, 0);
        aI[c] = MFMA(Ac, zi, aI[c], 0, 0, 0);
        aI[c] = MFMA(An, zr, aI[c], 0, 0, 0);
      } else {
        aR[c] = MFMA(An, zi, aR[c], 0, 0, 0);
        aI[c] = MFMA(Ac, zi, aI[c], 0, 0, 0);
        aI[c] = MFMA(As, zr, aI[c], 0, 0, 0);
      }
    }
  }
}

__global__ __launch_bounds__(1024, 8) void k_mid(const unsigned int* __restrict__ A,
                                                 unsigned int* __restrict__ Bp,
                                                 const unsigned short* __restrict__ wf,
                                                 const float* __restrict__ bpk) {
  __shared__ unsigned short Rb[13312], Ib[13312];  // 53.2 KB plane (layout morphs)
  __shared__ unsigned short WfX[2][12 * 512];      // 24.6 KB double-buffered weight frags
  const int kv = blockIdx.x, n = blockIdx.y, b = blockIdx.z, t = threadIdx.x;
  const int w = t >> 6, lane = t & 63, l15 = lane & 15, lg = lane >> 4;
  const int rt = w >> 1, cb = (w & 1) * 3;         // ko/row tile 0..7, nt-half base
  const size_t pbase = ((size_t)b * NPOS + kv) * HD + n * 96;
  const unsigned short* tm = wf + TM_OFF;
  const unsigned short* wf1 = wf + WF_OFF + (size_t)n * (72 * 512);
  const unsigned short* wf2 = wf + WF_OFF + (size_t)(8 + n) * (72 * 512);

  // ---- P0: stage plane (row pairs -> dword LDS writes) + load L1 kk'=0 frags
  {
    unsigned int* Rb32 = (unsigned int*)Rb;
    unsigned int* Ib32 = (unsigned int*)Ib;
    for (int idx = t; idx < 64 * 96; idx += 1024) {
      int r2 = idx / 96, ch = idx - r2 * 96;
      unsigned int u0 = A[pbase + (size_t)(2 * r2) * (WC * HD) + ch];
      unsigned int u1 = A[pbase + (size_t)(2 * r2 + 1) * (WC * HD) + ch];
      Rb32[ch * 68 + r2] = (u0 & 0xffffu) | (u1 << 16);
      Ib32[ch * 68 + r2] = (u0 >> 16) | (u1 & 0xffff0000u);
    }
    if (t < 768) ((int4*)WfX[0])[t] = ((const int4*)(wf1 + 0 * 12 * 512))[t];
  }
  __syncthreads();                                  // B1

  // ---- P1: GEMM-1 fwd H-DFT + load L1 kk'=1
  f32x4 aR[3], aI[3];
#pragma unroll
  for (int c = 0; c < 3; ++c) { aR[c] = {0.f,0.f,0.f,0.f}; aI[c] = {0.f,0.f,0.f,0.f}; }
  dft_gemm16<1>(Rb, Ib, tm, rt, cb, lane, aR, aI);
  if (t < 768) ((int4*)WfX[1])[t] = ((const int4*)(wf1 + 1 * 12 * 512))[t];
  __syncthreads();                                  // B2 (plane [ch][r] reads done)

  // ---- P2: writeback as [pos][ch] (stride 104)
#pragma unroll
  for (int c = 0; c < 3; ++c)
#pragma unroll
    for (int r = 0; r < 4; ++r) {
      int row = rt * 16 + lg * 4 + r, ch = (cb + c) * 16 + l15;
      Rb[row * 104 + ch] = f2bf(aR[c][r]);
      Ib[row * 104 + ch] = f2bf(aI[c][r]);
    }
  __syncthreads();                                  // B3

  const int row_a = (rt * 16 + l15) * 104;
  f32x4 acc[6];
#pragma unroll
  for (int i = 0; i < 3; ++i) {
    float bv = bpk[n * 192 + (cb + i) * 16 + l15];
    acc[i] = { bv, bv, bv, bv };
    bv = bpk[n * 192 + (cb + i + 6) * 16 + l15];
    acc[3 + i] = { bv, bv, bv, bv };
  }

  // MLP kk-pair step: MFMA kk=k0 (A=Rb row) and kk=k0+3 (A=Ib row) vs buffer's 12 frags
#define MLP_PAIR(k0, BUF)                                                        \
  {                                                                              \
    short8 aRf = *(const short8*)&Rb[row_a + (k0) * 32 + lg * 8];                \
    short8 aIf = *(const short8*)&Ib[row_a + (k0) * 32 + lg * 8];                \
    _Pragma("unroll")                                                            \
    for (int i = 0; i < 6; ++i) {                                                \
      int nt = cb + (i < 3 ? i : i + 3);                                         \
      short8 b0 = *(const short8*)&(BUF)[nt * 512 + lane * 8];                   \
      acc[i] = MFMA(aRf, b0, acc[i], 0, 0, 0);                                   \
      int nt2 = (nt < 6) ? nt + 6 : nt - 6;                                      \
      int4 nb = *(const int4*)&(BUF)[nt2 * 512 + lane * 8];                      \
      if (nt < 6) { nb.x ^= 0x80008000; nb.y ^= 0x80008000;                      \
                    nb.z ^= 0x80008000; nb.w ^= 0x80008000; }                    \
      acc[i] = MFMA(aIf, __builtin_bit_cast(short8, nb), acc[i], 0, 0, 0);       \
    }                                                                            \
  }

  // ---- P3..P5: MLP layer 1 (three kk-pair sub-phases, frag prefetch)
  MLP_PAIR(0, WfX[0]);
  __syncthreads();                                  // B4
  MLP_PAIR(1, WfX[1]);
  if (t < 768) ((int4*)WfX[0])[t] = ((const int4*)(wf1 + 2 * 12 * 512))[t];
  __syncthreads();                                  // B5
  MLP_PAIR(2, WfX[0]);
  if (t < 768) ((int4*)WfX[1])[t] = ((const int4*)(wf2 + 0 * 12 * 512))[t];
  __syncthreads();                                  // B6 (all L1 plane reads done)

  // ---- P6: relu -> [pos][ch] + load L2 kk'=1
#pragma unroll
  for (int i = 0; i < 3; ++i)
#pragma unroll
    for (int r = 0; r < 4; ++r) {
      int row = rt * 16 + lg * 4 + r, ch = (cb + i) * 16 + l15;
      Rb[row * 104 + ch] = f2bf(fmaxf(acc[i][r], 0.f));
      Ib[row * 104 + ch] = f2bf(fmaxf(acc[3 + i][r], 0.f));
    }
  if (t < 768) ((int4*)WfX[0])[t] = ((const int4*)(wf2 + 1 * 12 * 512))[t];
  __syncthreads();                                  // B7

  // ---- P7..P9: MLP layer 2
#pragma unroll
  for (int i = 0; i < 3; ++i) {
    float bv = bpk[(8 + n) * 192 + (cb + i) * 16 + l15];
    acc[i] = { bv, bv, bv, bv };
    bv = bpk[(8 + n) * 192 + (cb + i + 6) * 16 + l15];
    acc[3 + i] = { bv, bv, bv, bv };
  }
  MLP_PAIR(0, WfX[1]);
  __syncthreads();                                  // B8
  MLP_PAIR(1, WfX[0]);
  if (t < 768) ((int4*)WfX[1])[t] = ((const int4*)(wf2 + 2 * 12 * 512))[t];
  __syncthreads();                                  // B9
  MLP_PAIR(2, WfX[1]);
  __syncthreads();                                  // B10 (all L2 plane reads done)

  // ---- P10: softshrink -> [ch][ko] (stride 136)
#pragma unroll
  for (int r = 0; r < 4; ++r) {
    int ko = rt * 16 + lg * 4 + r;
    float kus = (ko >= 64) ? (float)(ko - 128) : (float)ko;
    float k2v = kus * kus + (float)(kv * kv);
    float thr = fmaxf(0.01f * expf(-0.00125f * k2v), 0.0005f);
#pragma unroll
    for (int i = 0; i < 3; ++i) {
      float mr = acc[i][r], mi = acc[3 + i][r];
      float mag = sqrtf(mr * mr + mi * mi + 1e-8f);
      float sf = fmaxf(mag - thr, 0.f) / mag;
      int ch = (cb + i) * 16 + l15;
      Rb[ch * 136 + ko] = f2bf(mr * sf);
      Ib[ch * 136 + ko] = f2bf(mi * sf);
    }
  }
  __syncthreads();                                  // B11

  // ---- P11: GEMM-2 inverse H-DFT -> Bp plane
#pragma unroll
  for (int c = 0; c < 3; ++c) { aR[c] = {0.f,0.f,0.f,0.f}; aI[c] = {0.f,0.f,0.f,0.f}; }
  dft_gemm16<0>(Rb, Ib, tm, rt, cb, lane, aR, aI);
#pragma unroll
  for (int c = 0; c < 3; ++c)
#pragma unroll
    for (int r = 0; r < 4; ++r) {
      int rr = rt * 16 + lg * 4 + r, ch = (cb + c) * 16 + l15;
      Bp[pbase + (size_t)rr * (WC * HD) + ch] = pack2(aR[c][r], aI[c][r]);
    }
#undef MLP_PAIR
}

extern "C" void kernel_launch(void* const* d_in, const int* in_sizes, int n_in,
                              void* d_out, int out_size, void* d_ws, size_t ws_size,
                              hipStream_t stream) {
  const float* x  = (const float*)d_in[0];
  const float* w1 = (const float*)d_in[1];
  const float* b1 = (const float*)d_in[2];
  const float* w2 = (const float*)d_in[3];
  const float* b2 = (const float*)d_in[4];
  float* out = (float*)d_out;
  unsigned int* A  = (unsigned int*)d_ws;           // 102.2 MB forward spectrum
  unsigned int* Bp = A + A_UINTS;                   // 102.2 MB post-MLP spectrum

  // baked tables after the two planes (~1.4 MB) — nothing else writes there
  unsigned short* wf = (unsigned short*)(Bp + A_UINTS);
  float* bpk = (float*)(wf + WF_END_U16);

  k_prep<<<19, 256, 0, stream>>>(w1, b1, w2, b2, wf, bpk);
  k_fft_w<<<dim3(HH, HD / 64, 4), 256, 0, stream>>>(x, A, wf);
  k_mid<<<dim3(WC, NBLK, 4), 1024, 0, stream>>>(A, Bp, wf, bpk);
  k_ifft_w<<<dim3(HH, HD / 64, 4), 256, 0, stream>>>(A, Bp, out, wf);
}

// Round 11
// 405.071 us; speedup vs baseline: 1.1576x; 1.1576x over previous
//
#include <hip/hip_runtime.h>
#include <hip/hip_bf16.h>
#include <math.h>

// AFNO2D: rfft2(128x128, ortho) -> blockdiag complex MLP (8 x 96) -> softshrink -> irfft2 -> +bias
// B=4, H=W=128, C=768.  ALL transforms are MFMA GEMMs against baked bf16 matrices.
// Planes in ws (packed bf16 re|im per uint, [b][pos=h*65+kw][c]):
//   A = forward spectrum (written by k_fft_w, read-only afterwards)
//   Bp = post-MLP spectrum (written by k_mid)
// Bias via spectral identity: irfft_w(rfft_w(x)) = x, so k_ifft_w transforms (A + Bp).
// k_mid v5: 76 KB LDS (double-buffered 12-frag weight staging) targeting 2 WG/CU, but with
// round-9's register profile: plain __launch_bounds__(1024) and simple per-row P0 staging.
// Round-10 post-mortem: __launch_bounds__(1024,8) clamped arch VGPRs to 32 -> scratch spills
// (+125MB FETCH, 510MB WRITE) which ate the whole occupancy win.

#define HD   768
#define NBLK 8
#define HH   128
#define WW   128
#define WC   65
#define NPOS (HH * WC)

constexpr float SC    = 0.08838834764831845f;      // 1/sqrt(128)
constexpr float TWOPI = 6.28318530717958647692f;

// table layout (ushort offsets from wf base)
constexpr int TM_OFF     = 0;        // H-DFT: 96 frags = part(3:cos,sin,-sin) x kot(8) x kk(4)
constexpr int TW_OFF     = 49152;    // W-rfft: 40 frags = mt(10) x kk(4)
constexpr int TWI_OFF    = 69632;    // W-irfft: 40 frags = mt(8) x kk(5)
constexpr int WF_OFF     = 90112;    // MLP: 16 (layer,n) x 72 frags (k_mid uses kk' 0..2 = 36)
constexpr int WF_END_U16 = 679936;   // WF_OFF + 16*72*512
constexpr size_t A_UINTS = (size_t)4 * NPOS * HD;  // 102.2 MB per plane

typedef __attribute__((ext_vector_type(8))) short short8;
typedef __attribute__((ext_vector_type(4))) float f32x4;

#define MFMA __builtin_amdgcn_mfma_f32_16x16x32_bf16

static __device__ inline unsigned short f2bf(float f) {
  __hip_bfloat16 h = __float2bfloat16(f);
  return __builtin_bit_cast(unsigned short, h);
}
static __device__ inline unsigned int pack2(float re, float im) {
  return (unsigned int)f2bf(re) | ((unsigned int)f2bf(im) << 16);
}
static __device__ inline float lo2f(unsigned int u) {
  return __builtin_bit_cast(float, u << 16);
}
static __device__ inline float hi2f(unsigned int u) {
  return __builtin_bit_cast(float, u & 0xffff0000u);
}

// ================= k_prep: bake all MFMA fragment images =================
__global__ __launch_bounds__(256) void k_prep(const float* __restrict__ w1,
                                              const float* __restrict__ b1,
                                              const float* __restrict__ w2,
                                              const float* __restrict__ b2,
                                              unsigned short* __restrict__ wf,
                                              float* __restrict__ bpk) {
  const int blk = blockIdx.x, t = threadIdx.x;
  if (blk < 16) {                      // MLP Waug B-frags (full 72) + biases
    const int layer = blk >> 3, n = blk & 7;
    const float* w  = layer ? w2 : w1;
    const float* bs = layer ? b2 : b1;
    unsigned short* dst = wf + WF_OFF + (size_t)blk * (72 * 512);
    for (int e = t; e < 72 * 512; e += 256) {
      int f = e >> 9, idx = e & 511;
      int kk = f / 12, nt = f - kk * 12;
      int lane = idx >> 3, j = idx & 7;
      int k  = kk * 32 + (lane >> 4) * 8 + j;     // 0..191
      int cc = nt * 16 + (lane & 15);             // 0..191
      float v;
      if (k < 96) v = (cc < 96) ? w[(size_t)n * 9216 + k * 96 + cc]
                                : w[(size_t)(8 + n) * 9216 + k * 96 + (cc - 96)];
      else        v = (cc < 96) ? -w[(size_t)(8 + n) * 9216 + (k - 96) * 96 + cc]
                                :  w[(size_t)n * 9216 + (k - 96) * 96 + (cc - 96)];
      dst[e] = f2bf(v);
    }
    for (int c = t; c < 192; c += 256)
      bpk[blk * 192 + c] = (c < 96) ? bs[n * 96 + c] : bs[(8 + n) * 96 + (c - 96)];
  } else if (blk == 16) {              // H-DFT twiddles: 3 parts x 32 (kot*4+kk)
    for (int e = t; e < 96 * 512; e += 256) {
      int f = e >> 9, idx = e & 511;
      int part = f >> 5, rem = f & 31, kot = rem >> 2, kk = rem & 3;
      int lane = idx >> 3, j = idx & 7;
      int ko = kot * 16 + (lane & 15);
      int r  = kk * 32 + (lane >> 4) * 8 + j;     // 0..127
      float sn, cs; sincosf((TWOPI / 128.f) * (float)((ko * r) & 127), &sn, &cs);
      float v = (part == 0) ? cs : (part == 1) ? sn : -sn;
      wf[TM_OFF + (size_t)f * 512 + idx] = f2bf(v * SC);
    }
  } else if (blk == 17) {              // W-rfft matrix: rows 0..79 = re, 80..159 = im
    for (int e = t; e < 40 * 512; e += 256) {
      int f = e >> 9, idx = e & 511;
      int mt = f >> 2, kk = f & 3;
      int lane = idx >> 3, j = idx & 7;
      int row = mt * 16 + (lane & 15);
      int r   = kk * 32 + (lane >> 4) * 8 + j;    // 0..127
      int kor = (row < 80) ? row : row - 80;
      float sn, cs; sincosf((TWOPI / 128.f) * (float)((kor * r) & 127), &sn, &cs);
      wf[TW_OFF + (size_t)f * 512 + idx] = f2bf((row < 80 ? cs : -sn) * SC);
    }
  } else {                             // W-irfft matrix: K = [re 0..79 | im 0..79]
    for (int e = t; e < 40 * 512; e += 256) {
      int f = e >> 9, idx = e & 511;
      int mt = f / 5, kk = f - mt * 5;
      int lane = idx >> 3, j = idx & 7;
      int wr = mt * 16 + (lane & 15);
      int k  = kk * 32 + (lane >> 4) * 8 + j;     // 0..159
      float v = 0.f;
      if (k < 80) {
        int kb = k;
        if (kb <= 64) {
          float sn, cs; sincosf((TWOPI / 128.f) * (float)((wr * kb) & 127), &sn, &cs);
          v = SC * ((kb == 0 || kb == 64) ? 1.f : 2.f) * cs;
        }
      } else {
        int kb = k - 80;                           // imag of bins 0,64 ignored (c2r)
        if (kb >= 1 && kb <= 63) {
          float sn, cs; sincosf((TWOPI / 128.f) * (float)((wr * kb) & 127), &sn, &cs);
          v = -2.f * SC * sn;
        }
      }
      wf[TWI_OFF + (size_t)f * 512 + idx] = f2bf(v);
    }
  }
}

// ================= k_fft_w: rfft along W via GEMM, x -> packed A =================
__global__ __launch_bounds__(256) void k_fft_w(const float* __restrict__ x,
                                               unsigned int* __restrict__ A,
                                               const unsigned short* __restrict__ wf) {
  __shared__ unsigned short Xt[64 * 136];          // [ch][r] bf16
  const int h = blockIdx.x, c0 = blockIdx.y * 64, b = blockIdx.z, t = threadIdx.x;
  const int wv = t >> 6, lane = t & 63, l15 = lane & 15, lg = lane >> 4;
  const float* xp = x + ((size_t)(b * HH + h)) * WW * HD + c0;
  for (int idx = t; idx < 128 * 64; idx += 256) {
    int r = idx >> 6, ch = idx & 63;
    Xt[ch * 136 + r] = f2bf(xp[(size_t)r * HD + ch]);
  }
  __syncthreads();
  const unsigned short* tw = wf + TW_OFF;
  f32x4 acc[10];
#pragma unroll
  for (int m = 0; m < 10; ++m) acc[m] = { 0.f, 0.f, 0.f, 0.f };
#pragma unroll
  for (int kk = 0; kk < 4; ++kk) {
    short8 bq = *(const short8*)&Xt[(wv * 16 + l15) * 136 + kk * 32 + lg * 8];
#pragma unroll
    for (int m = 0; m < 10; ++m) {
      short8 a = *(const short8*)&tw[(size_t)(m * 4 + kk) * 512 + lane * 8];
      acc[m] = MFMA(a, bq, acc[m], 0, 0, 0);
    }
  }
  unsigned int* Ao = A + ((size_t)b * NPOS + h * WC) * HD + c0 + wv * 16 + l15;
#pragma unroll
  for (int q = 0; q < 5; ++q)
#pragma unroll
    for (int r = 0; r < 4; ++r) {
      int ko = q * 16 + lg * 4 + r;
      if (ko <= 64) Ao[(size_t)ko * HD] = pack2(acc[q][r], acc[5 + q][r]);
    }
}

// ================= k_ifft_w: irfft along W of (A + Bp) via GEMM (spectral bias) ========
__global__ __launch_bounds__(256) void k_ifft_w(const unsigned int* __restrict__ A,
                                                const unsigned int* __restrict__ Bp,
                                                float* __restrict__ out,
                                                const unsigned short* __restrict__ wf) {
  __shared__ unsigned short Zt[64 * 168];          // [ch][k-stack 160]
  const int h = blockIdx.x, c0 = blockIdx.y * 64, b = blockIdx.z, t = threadIdx.x;
  const int wv = t >> 6, lane = t & 63, l15 = lane & 15, lg = lane >> 4;
  const size_t base = ((size_t)b * NPOS + h * WC) * HD + c0;
  for (int idx = t; idx < 65 * 64; idx += 256) {
    int kb = idx >> 6, ch = idx & 63;
    unsigned int uA = A[base + (size_t)kb * HD + ch];
    unsigned int uB = Bp[base + (size_t)kb * HD + ch];
    float re = lo2f(uA) + lo2f(uB);
    float im = hi2f(uA) + hi2f(uB);
    Zt[ch * 168 + kb]      = f2bf(re);
    Zt[ch * 168 + 80 + kb] = (kb == 0 || kb == 64) ? (unsigned short)0 : f2bf(im);
  }
  for (int idx = t; idx < 64 * 32; idx += 256) {   // zero-pad k 65..79 both halves
    int ch = idx >> 5, q = idx & 31;
    if (q < 30) {
      int kb = 65 + (q % 15), half = q / 15;
      Zt[ch * 168 + half * 80 + kb] = 0;
    }
  }
  __syncthreads();
  const unsigned short* twi = wf + TWI_OFF;
  f32x4 acc[8];
#pragma unroll
  for (int m = 0; m < 8; ++m) acc[m] = { 0.f, 0.f, 0.f, 0.f };
#pragma unroll
  for (int kk = 0; kk < 5; ++kk) {
    short8 bq = *(const short8*)&Zt[(wv * 16 + l15) * 168 + kk * 32 + lg * 8];
#pragma unroll
    for (int m = 0; m < 8; ++m) {
      short8 a = *(const short8*)&twi[(size_t)(m * 5 + kk) * 512 + lane * 8];
      acc[m] = MFMA(a, bq, acc[m], 0, 0, 0);
    }
  }
#pragma unroll
  for (int m = 0; m < 8; ++m)
#pragma unroll
    for (int r = 0; r < 4; ++r) {
      int wr = m * 16 + lg * 4 + r;
      size_t go = (((size_t)(b * HH + h)) * WW + wr) * HD + c0 + wv * 16 + l15;
      out[go] = acc[m][r];
    }
}

// ================= k_mid: H-DFT fwd + MLP + softshrink + H-DFT inv =====================
template <int FWD>
static __device__ inline void dft_gemm16(const unsigned short* Rb, const unsigned short* Ib,
                                         const unsigned short* tm, int rt, int cb, int lane,
                                         f32x4* aR, f32x4* aI) {
  const int l15 = lane & 15, lg = lane >> 4;
#pragma unroll
  for (int kkr = 0; kkr < 4; ++kkr) {
    const int r0 = kkr * 32 + lg * 8;
    short8 Ac = *(const short8*)&tm[(size_t)(0 * 32 + rt * 4 + kkr) * 512 + lane * 8];
    short8 As = *(const short8*)&tm[(size_t)(1 * 32 + rt * 4 + kkr) * 512 + lane * 8];
    short8 An = *(const short8*)&tm[(size_t)(2 * 32 + rt * 4 + kkr) * 512 + lane * 8];
#pragma unroll
    for (int c = 0; c < 3; ++c) {
      short8 zr = *(const short8*)&Rb[((cb + c) * 16 + l15) * 136 + r0];
      short8 zi = *(const short8*)&Ib[((cb + c) * 16 + l15) * 136 + r0];
      aR[c] = MFMA(Ac, zr, aR[c], 0, 0, 0);
      if constexpr (FWD) {
        aR[c] = MFMA(As, zi, aR[c], 0, 0, 0);
        aI[c] = MFMA(Ac, zi, aI[c], 0, 0, 0);
        aI[c] = MFMA(An, zr, aI[c], 0, 0, 0);
      } else {
        aR[c] = MFMA(An, zi, aR[c], 0, 0, 0);
        aI[c] = MFMA(Ac, zi, aI[c], 0, 0, 0);
        aI[c] = MFMA(As, zr, aI[c], 0, 0, 0);
      }
    }
  }
}

__global__ __launch_bounds__(1024) void k_mid(const unsigned int* __restrict__ A,
                                              unsigned int* __restrict__ Bp,
                                              const unsigned short* __restrict__ wf,
                                              const float* __restrict__ bpk) {
  __shared__ unsigned short Rb[13312], Ib[13312];  // 53.2 KB plane (layout morphs)
  __shared__ unsigned short WfX[2][12 * 512];      // 24.6 KB double-buffered weight frags
  const int kv = blockIdx.x, n = blockIdx.y, b = blockIdx.z, t = threadIdx.x;
  const int w = t >> 6, lane = t & 63, l15 = lane & 15, lg = lane >> 4;
  const int rt = w >> 1, cb = (w & 1) * 3;         // ko/row tile 0..7, nt-half base
  const size_t pbase = ((size_t)b * NPOS + kv) * HD + n * 96;
  const unsigned short* tm = wf + TM_OFF;
  const unsigned short* wf1 = wf + WF_OFF + (size_t)n * (72 * 512);
  const unsigned short* wf2 = wf + WF_OFF + (size_t)(8 + n) * (72 * 512);

  // ---- P0: stage plane (simple per-row form, low reg pressure) + load L1 kk'=0 frags
  for (int idx = t; idx < 128 * 96; idx += 1024) {
    int r = idx / 96, ch = idx - r * 96;
    unsigned int u = A[pbase + (size_t)r * (WC * HD) + ch];
    Rb[ch * 136 + r] = (unsigned short)(u & 0xffffu);
    Ib[ch * 136 + r] = (unsigned short)(u >> 16);
  }
  if (t < 768) ((int4*)WfX[0])[t] = ((const int4*)(wf1 + 0 * 12 * 512))[t];
  __syncthreads();                                  // B1

  // ---- P1: GEMM-1 fwd H-DFT + load L1 kk'=1
  f32x4 aR[3], aI[3];
#pragma unroll
  for (int c = 0; c < 3; ++c) { aR[c] = {0.f,0.f,0.f,0.f}; aI[c] = {0.f,0.f,0.f,0.f}; }
  dft_gemm16<1>(Rb, Ib, tm, rt, cb, lane, aR, aI);
  if (t < 768) ((int4*)WfX[1])[t] = ((const int4*)(wf1 + 1 * 12 * 512))[t];
  __syncthreads();                                  // B2 (plane [ch][r] reads done)

  // ---- P2: writeback as [pos][ch] (stride 104)
#pragma unroll
  for (int c = 0; c < 3; ++c)
#pragma unroll
    for (int r = 0; r < 4; ++r) {
      int row = rt * 16 + lg * 4 + r, ch = (cb + c) * 16 + l15;
      Rb[row * 104 + ch] = f2bf(aR[c][r]);
      Ib[row * 104 + ch] = f2bf(aI[c][r]);
    }
  __syncthreads();                                  // B3

  const int row_a = (rt * 16 + l15) * 104;
  f32x4 acc[6];
#pragma unroll
  for (int i = 0; i < 3; ++i) {
    float bv = bpk[n * 192 + (cb + i) * 16 + l15];
    acc[i] = { bv, bv, bv, bv };
    bv = bpk[n * 192 + (cb + i + 6) * 16 + l15];
    acc[3 + i] = { bv, bv, bv, bv };
  }

  // MLP kk-pair step: MFMA kk=k0 (A=Rb row) and kk=k0+3 (A=Ib row) vs buffer's 12 frags
#define MLP_PAIR(k0, BUF)                                                        \
  {                                                                              \
    short8 aRf = *(const short8*)&Rb[row_a + (k0) * 32 + lg * 8];                \
    short8 aIf = *(const short8*)&Ib[row_a + (k0) * 32 + lg * 8];                \
    _Pragma("unroll")                                                            \
    for (int i = 0; i < 6; ++i) {                                                \
      int nt = cb + (i < 3 ? i : i + 3);                                         \
      short8 b0 = *(const short8*)&(BUF)[nt * 512 + lane * 8];                   \
      acc[i] = MFMA(aRf, b0, acc[i], 0, 0, 0);                                   \
      int nt2 = (nt < 6) ? nt + 6 : nt - 6;                                      \
      int4 nb = *(const int4*)&(BUF)[nt2 * 512 + lane * 8];                      \
      if (nt < 6) { nb.x ^= 0x80008000; nb.y ^= 0x80008000;                      \
                    nb.z ^= 0x80008000; nb.w ^= 0x80008000; }                    \
      acc[i] = MFMA(aIf, __builtin_bit_cast(short8, nb), acc[i], 0, 0, 0);       \
    }                                                                            \
  }

  // ---- P3..P5: MLP layer 1 (three kk-pair sub-phases, frag prefetch)
  MLP_PAIR(0, WfX[0]);
  __syncthreads();                                  // B4
  MLP_PAIR(1, WfX[1]);
  if (t < 768) ((int4*)WfX[0])[t] = ((const int4*)(wf1 + 2 * 12 * 512))[t];
  __syncthreads();                                  // B5
  MLP_PAIR(2, WfX[0]);
  if (t < 768) ((int4*)WfX[1])[t] = ((const int4*)(wf2 + 0 * 12 * 512))[t];
  __syncthreads();                                  // B6 (all L1 plane reads done)

  // ---- P6: relu -> [pos][ch] + load L2 kk'=1
#pragma unroll
  for (int i = 0; i < 3; ++i)
#pragma unroll
    for (int r = 0; r < 4; ++r) {
      int row = rt * 16 + lg * 4 + r, ch = (cb + i) * 16 + l15;
      Rb[row * 104 + ch] = f2bf(fmaxf(acc[i][r], 0.f));
      Ib[row * 104 + ch] = f2bf(fmaxf(acc[3 + i][r], 0.f));
    }
  if (t < 768) ((int4*)WfX[0])[t] = ((const int4*)(wf2 + 1 * 12 * 512))[t];
  __syncthreads();                                  // B7

  // ---- P7..P9: MLP layer 2
#pragma unroll
  for (int i = 0; i < 3; ++i) {
    float bv = bpk[(8 + n) * 192 + (cb + i) * 16 + l15];
    acc[i] = { bv, bv, bv, bv };
    bv = bpk[(8 + n) * 192 + (cb + i + 6) * 16 + l15];
    acc[3 + i] = { bv, bv, bv, bv };
  }
  MLP_PAIR(0, WfX[1]);
  __syncthreads();                                  // B8
  MLP_PAIR(1, WfX[0]);
  if (t < 768) ((int4*)WfX[1])[t] = ((const int4*)(wf2 + 2 * 12 * 512))[t];
  __syncthreads();                                  // B9
  MLP_PAIR(2, WfX[1]);
  __syncthreads();                                  // B10 (all L2 plane reads done)

  // ---- P10: softshrink -> [ch][ko] (stride 136)
#pragma unroll
  for (int r = 0; r < 4; ++r) {
    int ko = rt * 16 + lg * 4 + r;
    float kus = (ko >= 64) ? (float)(ko - 128) : (float)ko;
    float k2v = kus * kus + (float)(kv * kv);
    float thr = fmaxf(0.01f * expf(-0.00125f * k2v), 0.0005f);
#pragma unroll
    for (int i = 0; i < 3; ++i) {
      float mr = acc[i][r], mi = acc[3 + i][r];
      float mag = sqrtf(mr * mr + mi * mi + 1e-8f);
      float sf = fmaxf(mag - thr, 0.f) / mag;
      int ch = (cb + i) * 16 + l15;
      Rb[ch * 136 + ko] = f2bf(mr * sf);
      Ib[ch * 136 + ko] = f2bf(mi * sf);
    }
  }
  __syncthreads();                                  // B11

  // ---- P11: GEMM-2 inverse H-DFT -> Bp plane
#pragma unroll
  for (int c = 0; c < 3; ++c) { aR[c] = {0.f,0.f,0.f,0.f}; aI[c] = {0.f,0.f,0.f,0.f}; }
  dft_gemm16<0>(Rb, Ib, tm, rt, cb, lane, aR, aI);
#pragma unroll
  for (int c = 0; c < 3; ++c)
#pragma unroll
    for (int r = 0; r < 4; ++r) {
      int rr = rt * 16 + lg * 4 + r, ch = (cb + c) * 16 + l15;
      Bp[pbase + (size_t)rr * (WC * HD) + ch] = pack2(aR[c][r], aI[c][r]);
    }
#undef MLP_PAIR
}

extern "C" void kernel_launch(void* const* d_in, const int* in_sizes, int n_in,
                              void* d_out, int out_size, void* d_ws, size_t ws_size,
                              hipStream_t stream) {
  const float* x  = (const float*)d_in[0];
  const float* w1 = (const float*)d_in[1];
  const float* b1 = (const float*)d_in[2];
  const float* w2 = (const float*)d_in[3];
  const float* b2 = (const float*)d_in[4];
  float* out = (float*)d_out;
  unsigned int* A  = (unsigned int*)d_ws;           // 102.2 MB forward spectrum
  unsigned int* Bp = A + A_UINTS;                   // 102.2 MB post-MLP spectrum

  // baked tables after the two planes (~1.4 MB) — nothing else writes there
  unsigned short* wf = (unsigned short*)(Bp + A_UINTS);
  float* bpk = (float*)(wf + WF_END_U16);

  k_prep<<<19, 256, 0, stream>>>(w1, b1, w2, b2, wf, bpk);
  k_fft_w<<<dim3(HH, HD / 64, 4), 256, 0, stream>>>(x, A, wf);
  k_mid<<<dim3(WC, NBLK, 4), 1024, 0, stream>>>(A, Bp, wf, bpk);
  k_ifft_w<<<dim3(HH, HD / 64, 4), 256, 0, stream>>>(A, Bp, out, wf);
}